// Round 19
// baseline (83.100 us; speedup 1.0000x reference)
//
#include <hip/hip_runtime.h>
#include <math.h>

#define N_DIM 64
#define C_DIM 512
#define K_DIM 64
#define P_DIM 900
#define P_PAD 928          // 29 * 32 == PTILES*32 exactly
#define PTILES 29          // assign p-blocks of 32

typedef __attribute__((ext_vector_type(8))) short short8;   // 8 bf16 = 4 VGPR
typedef __attribute__((ext_vector_type(4))) float f32x4;    // MFMA C/D + loads
typedef __attribute__((ext_vector_type(4))) uint  u32x4;
typedef __attribute__((ext_vector_type(2))) float f32x2;

#define A2_ELEMS   ((size_t)N_DIM * K_DIM * P_PAD)

// fp32 -> bf16 bits, round-to-nearest-even (inputs finite)
__device__ inline ushort f2bf(float f) {
  uint u = __builtin_bit_cast(uint, f);
  u += 0x7FFFu + ((u >> 16) & 1u);
  return (ushort)(u >> 16);
}
__device__ inline uint pk2(float a, float b) {
  return (uint)f2bf(a) | ((uint)f2bf(b) << 16);
}

// async global->LDS DMA, 16B per lane; LDS dest = wave-uniform base + lane*16
__device__ __forceinline__ void gload16(const float* g, float* lds_base) {
  __builtin_amdgcn_global_load_lds(
      (const __attribute__((address_space(1))) void*)g,
      (__attribute__((address_space(3))) void*)lds_base, 16, 0, 0);
}

// ---------------------------------------------------------------------------
// Kernel A (v11): round-18 evidence: L3-hot replays ALSO take 67us -> not
// HBM-bound; stall-bound at 18% occupancy (67KB LDS=2 blk/CU, grid 3.75/CU).
// v11 raises TLP on both axes: 32-px tiles (PTILES=29, 7.25 blk/CU grid) and
// 16KB chunks (32KB dbuf -> 4 blk/CU LDS) with launch_bounds(256,4).
// W-frags: per-chunk pipelined global loads (raw f32x4 prefetched alongside
// staging, converted after barrier) instead of a resident 64-VGPR array.
// T4 counted vmcnt kept: outstanding at wait = 4 stage + 8 Wraw = vmcnt(12).
// LDS XOR-swizzle both-sides (m201): write px-group g^=swz at source addr,
// read byte ^= swz<<4, swz=(row>>3)&7 -> 2-way-free ds_read_b64.
// ---------------------------------------------------------------------------
__global__ __launch_bounds__(256, 4) void netvlad_assign(
    const float* __restrict__ x, const float* __restrict__ w,
    ushort* __restrict__ a2, float* __restrict__ asum_part)
{
  const int n = blockIdx.y, bpt = blockIdx.x, p0 = bpt * 32;
  const int tid = threadIdx.x, wv = tid >> 6, lane = tid & 63;
  const int l15 = lane & 15, lhi = lane >> 4;
  const int r8 = lane >> 3, g = lane & 7;

  __shared__ float xs[2][4096];       // 2 x 16 KB chunks [128 c][32 px] fp32
  __shared__ float wredm[4][2][16];
  __shared__ float wreds[4][2][16];

  const float* xb = x + (size_t)n * C_DIM * P_DIM;
  const float* wrow = w + (size_t)(wv * 16 + l15) * C_DIM + lhi * 8;

  // stage chunk ch into buffer b: 4 gload16/wave; source-px swizzled so the
  // swizzled read finds its data (LDS dest stays linear per m104/m173).
#define STAGE(b, ch)                                                           \
  {                                                                            \
    _Pragma("unroll")                                                          \
    for (int i = 0; i < 4; ++i) {                                              \
      int rl  = wv * 32 + i * 8;                                               \
      int swz = (wv * 4 + i) & 7;                                              \
      int pld = p0 + ((g ^ swz) << 2);                                         \
      if (pld > P_DIM - 4) pld = P_DIM - 4;                                    \
      gload16(xb + (size_t)((ch) * 128 + rl + r8) * P_DIM + pld,               \
              &xs[b][rl * 32]);                                                \
    }                                                                          \
  }

  f32x4 acc[2];
  acc[0] = (f32x4){0.f, 0.f, 0.f, 0.f};
  acc[1] = (f32x4){0.f, 0.f, 0.f, 0.f};
  float ssqp[2] = {0.f, 0.f};
  short8 wf[4];

  // prologue: stage chunk 0, load+convert chunk-0 W (compiler waits only the
  // 8 W loads -- vmcnt(4) leaves the 4 staging loads in flight)
  STAGE(0, 0);
  {
    f32x4 wr[8];
#pragma unroll
    for (int kl = 0; kl < 4; ++kl) {
      wr[2 * kl]     = *(const f32x4*)(wrow + kl * 32);
      wr[2 * kl + 1] = *(const f32x4*)(wrow + kl * 32 + 4);
    }
#pragma unroll
    for (int kl = 0; kl < 4; ++kl) {
      u32x4 up;
      up[0] = pk2(wr[2 * kl][0], wr[2 * kl][1]);
      up[1] = pk2(wr[2 * kl][2], wr[2 * kl][3]);
      up[2] = pk2(wr[2 * kl + 1][0], wr[2 * kl + 1][1]);
      up[3] = pk2(wr[2 * kl + 1][2], wr[2 * kl + 1][3]);
      wf[kl] = __builtin_bit_cast(short8, up);
    }
  }

#pragma unroll
  for (int ch = 0; ch < 4; ++ch) {
    f32x4 wrn[8];
    if (ch + 1 < 4) {
      STAGE((ch + 1) & 1, ch + 1);
#pragma unroll
      for (int kl = 0; kl < 4; ++kl) {
        wrn[2 * kl]     = *(const f32x4*)(wrow + ((ch + 1) * 4 + kl) * 32);
        wrn[2 * kl + 1] = *(const f32x4*)(wrow + ((ch + 1) * 4 + kl) * 32 + 4);
      }
      // wait chunk-ch staging only: 4 stage(ch+1) + 8 Wraw(ch+1) younger
      asm volatile("s_waitcnt vmcnt(12)" ::: "memory");
    } else {
      asm volatile("s_waitcnt vmcnt(0)" ::: "memory");
    }
    __builtin_amdgcn_sched_barrier(0);
    __builtin_amdgcn_s_barrier();       // raw barrier: no vmcnt(0) drain

    const char* buf = (const char*)xs[ch & 1];
#pragma unroll
    for (int kl = 0; kl < 4; ++kl) {
      const int swz = ((kl * 4 + lhi) & 7) << 4;
      f32x2 rd[8];
#pragma unroll
      for (int j = 0; j < 8; ++j)
        rd[j] = *(const f32x2*)(buf + (kl * 32 + lhi * 8 + j) * 128
                                    + ((l15 * 8) ^ swz));
#pragma unroll
      for (int pt = 0; pt < 2; ++pt) {
        ssqp[pt] += rd[0][pt] * rd[0][pt] + rd[1][pt] * rd[1][pt]
                  + rd[2][pt] * rd[2][pt] + rd[3][pt] * rd[3][pt]
                  + rd[4][pt] * rd[4][pt] + rd[5][pt] * rd[5][pt]
                  + rd[6][pt] * rd[6][pt] + rd[7][pt] * rd[7][pt];
        u32x4 up;
        up[0] = pk2(rd[0][pt], rd[1][pt]); up[1] = pk2(rd[2][pt], rd[3][pt]);
        up[2] = pk2(rd[4][pt], rd[5][pt]); up[3] = pk2(rd[6][pt], rd[7][pt]);
        short8 xf = __builtin_bit_cast(short8, up);
        acc[pt] = __builtin_amdgcn_mfma_f32_16x16x32_bf16(wf[kl], xf, acc[pt], 0, 0, 0);
      }
    }
    // convert next chunk's W (auto vmcnt wait leaves stage(ch+1) in flight)
    if (ch + 1 < 4) {
#pragma unroll
      for (int kl = 0; kl < 4; ++kl) {
        u32x4 up;
        up[0] = pk2(wrn[2 * kl][0], wrn[2 * kl][1]);
        up[1] = pk2(wrn[2 * kl][2], wrn[2 * kl][3]);
        up[2] = pk2(wrn[2 * kl + 1][0], wrn[2 * kl + 1][1]);
        up[3] = pk2(wrn[2 * kl + 1][2], wrn[2 * kl + 1][3]);
        wf[kl] = __builtin_bit_cast(short8, up);
      }
    }
    __builtin_amdgcn_s_barrier();       // reads done before buf reuse
  }
#undef STAGE

  // ---- invn per pixel (px = p0 + 2*l15 + pt): reduce ssq over 4 lhi groups
  float linv[2];
#pragma unroll
  for (int pt = 0; pt < 2; ++pt) {
    float s = ssqp[pt];
    s += __shfl_xor(s, 16);
    s += __shfl_xor(s, 32);
    linv[pt] = 1.0f / fmaxf(sqrtf(s), 1e-12f);
  }

  // ---- softmax over k (64 values per pixel, cross-wave via LDS)
  float lg[2][4];
#pragma unroll
  for (int pt = 0; pt < 2; ++pt) {
    float m = -1e30f;
#pragma unroll
    for (int r = 0; r < 4; ++r) { lg[pt][r] = acc[pt][r] * linv[pt]; m = fmaxf(m, lg[pt][r]); }
    m = fmaxf(m, __shfl_xor(m, 16));
    m = fmaxf(m, __shfl_xor(m, 32));
    if (lhi == 0) wredm[wv][pt][l15] = m;
  }
  __syncthreads();
#pragma unroll
  for (int pt = 0; pt < 2; ++pt) {
    float m = fmaxf(fmaxf(wredm[0][pt][l15], wredm[1][pt][l15]),
                    fmaxf(wredm[2][pt][l15], wredm[3][pt][l15]));
    float s = 0.f;
#pragma unroll
    for (int r = 0; r < 4; ++r) { lg[pt][r] = __expf(lg[pt][r] - m); s += lg[pt][r]; }
    s += __shfl_xor(s, 16);
    s += __shfl_xor(s, 32);
    if (lhi == 0) wreds[wv][pt][l15] = s;
  }
  __syncthreads();

  ushort* a2b = a2 + (size_t)n * K_DIM * P_PAD;
  float asr[4] = {0.f, 0.f, 0.f, 0.f};
#pragma unroll
  for (int pt = 0; pt < 2; ++pt) {
    float stot = wreds[0][pt][l15] + wreds[1][pt][l15] +
                 wreds[2][pt][l15] + wreds[3][pt][l15];
    float rs = 1.0f / stot;
    int p = p0 + 2 * l15 + pt;
    bool vv = p < P_DIM;
#pragma unroll
    for (int r = 0; r < 4; ++r) {
      float a = lg[pt][r] * rs;
      if (vv) asr[r] += a;
      int k = wv * 16 + lhi * 4 + r;
      a2b[(size_t)k * P_PAD + p] = vv ? f2bf(a * linv[pt]) : (ushort)0;
    }
  }
#pragma unroll
  for (int r = 0; r < 4; ++r) {
    float v = asr[r];
    v += __shfl_xor(v, 1); v += __shfl_xor(v, 2);
    v += __shfl_xor(v, 4); v += __shfl_xor(v, 8);
    if (l15 == 0) {
      int k = wv * 16 + lhi * 4 + r;
      asum_part[((size_t)n * K_DIM + k) * PTILES + bpt] = v;
    }
  }
}

// ---------------------------------------------------------------------------
// Kernel B: agg[n,k,c] = sum_p a2[k,p]*x[c,p] via MFMA (unchanged; ~5us).
// ---------------------------------------------------------------------------
__global__ __launch_bounds__(256, 4) void netvlad_agg(
    const float* __restrict__ x, const ushort* __restrict__ a2,
    const float* __restrict__ asum_part, const float* __restrict__ cent,
    float* __restrict__ out)
{
  const int n = blockIdx.y, ct = blockIdx.x, c0 = ct * 64;
  const int tid = threadIdx.x, wave = tid >> 6, lane = tid & 63;
  const int l15 = lane & 15, lhi = lane >> 4;

  __shared__ float asum_s[64];
  if (tid < 64) {
    const float* ap = asum_part + ((size_t)n * K_DIM + tid) * PTILES;
    float s = 0.f;
    for (int j = 0; j < PTILES; ++j) s += ap[j];
    asum_s[tid] = s;
  }
  __syncthreads();

  f32x4 acc[4];
#pragma unroll
  for (int mt = 0; mt < 4; ++mt) acc[mt] = (f32x4){0.f, 0.f, 0.f, 0.f};

  const float*  xrow = x + (size_t)n * C_DIM * P_DIM
                         + (size_t)(c0 + wave * 16 + l15) * P_DIM;
  const ushort* ab   = a2 + (size_t)n * K_DIM * P_PAD;

  for (int ks = 0; ks < 29; ++ks) {
    int pb = ks * 32 + lhi * 8;
    short8 bfrag;
    if (pb + 8 <= P_DIM) {
      f32x4 f0 = *(const f32x4*)(xrow + pb);
      f32x4 f1 = *(const f32x4*)(xrow + pb + 4);
      u32x4 up;
      up[0] = pk2(f0[0], f0[1]); up[1] = pk2(f0[2], f0[3]);
      up[2] = pk2(f1[0], f1[1]); up[3] = pk2(f1[2], f1[3]);
      bfrag = __builtin_bit_cast(short8, up);
    } else {
#pragma unroll
      for (int j = 0; j < 8; ++j)
        bfrag[j] = (pb + j < P_DIM) ? (short)f2bf(xrow[pb + j]) : (short)0;
    }
#pragma unroll
    for (int mt = 0; mt < 4; ++mt) {
      short8 afrag = *(const short8*)(ab + (size_t)(mt * 16 + l15) * P_PAD
                                         + ks * 32 + lhi * 8);
      acc[mt] = __builtin_amdgcn_mfma_f32_16x16x32_bf16(afrag, bfrag, acc[mt], 0, 0, 0);
    }
  }

  const int c = c0 + wave * 16 + l15;
#pragma unroll
  for (int mt = 0; mt < 4; ++mt) {
#pragma unroll
    for (int r = 0; r < 4; ++r) {
      int k = mt * 16 + lhi * 4 + r;
      out[((size_t)n * K_DIM + k) * C_DIM + c] =
          acc[mt][r] - asum_s[k] * cent[(size_t)k * C_DIM + c];
    }
  }
}

extern "C" void kernel_launch(void* const* d_in, const int* in_sizes, int n_in,
                              void* d_out, int out_size, void* d_ws, size_t ws_size,
                              hipStream_t stream) {
  const float* x    = (const float*)d_in[0];
  const float* w    = (const float*)d_in[1];
  const float* cent = (const float*)d_in[2];
  float* out = (float*)d_out;

  ushort* a2        = (ushort*)d_ws;
  float*  asum_part = (float*)((char*)d_ws + A2_ELEMS * sizeof(ushort));

  netvlad_assign<<<dim3(PTILES, N_DIM), 256, 0, stream>>>(x, w, a2, asum_part);
  netvlad_agg   <<<dim3(8, N_DIM),      256, 0, stream>>>(x, a2, asum_part, cent, out);
}